// Round 2
// 973.751 us; speedup vs baseline: 1.1060x; 1.1060x over previous
//
#include <hip/hip_runtime.h>

#define M_MEMBERS 8
#define E_DIM 512
#define H_DIM 1024
#define V_DIM 4096
#define BI_DIM 4096

typedef __bf16 bf16x8 __attribute__((ext_vector_type(8)));
typedef float f32x4 __attribute__((ext_vector_type(4)));

__device__ __forceinline__ unsigned short f2b(float f) {
    unsigned u = __builtin_bit_cast(unsigned, f);
    u += 0x7fffu + ((u >> 16) & 1u);   // round-to-nearest-even
    return (unsigned short)(u >> 16);
}
__device__ __forceinline__ float b2f(unsigned short s) {
    return __builtin_bit_cast(float, (unsigned)s << 16);
}

// ---- async global->LDS, 16B per lane. LDS dest is wave-uniform base + lane*16.
typedef unsigned int __attribute__((address_space(1)))* gas_ptr;
typedef unsigned int __attribute__((address_space(3)))* las_ptr;

__device__ __forceinline__ void async16(const void* g, void* l) {
    __builtin_amdgcn_global_load_lds((gas_ptr)(unsigned long long)g,
                                     (las_ptr)(unsigned)(unsigned long long)l,
                                     16, 0, 0);
}

// ---------------- conversion: fp32 -> bf16, row-major ----------------
__global__ __launch_bounds__(256) void cvt_bf16(const float* __restrict__ in,
                                                unsigned short* __restrict__ out, long n) {
    long i = ((long)blockIdx.x * blockDim.x + threadIdx.x) * 4;
    if (i + 3 < n) {
        float4 v = *(const float4*)(in + i);
        ushort4 o;
        o.x = f2b(v.x); o.y = f2b(v.y); o.z = f2b(v.z); o.w = f2b(v.w);
        *(ushort4*)(out + i) = o;
    }
}

// ------- conversion: fp32 [z][R][C] -> bf16 [z][C][R] (transpose per member) -------
__global__ __launch_bounds__(256) void cvt_t(const float* __restrict__ in,
                                             unsigned short* __restrict__ out,
                                             int R, int C) {
    __shared__ unsigned short tile[32][34];
    const long mb = blockIdx.z;
    const float* inp = in + mb * (long)R * C;
    unsigned short* outp = out + mb * (long)R * C;
    const int c0 = blockIdx.x * 32, r0 = blockIdx.y * 32;
    const int tx = threadIdx.x, ty = threadIdx.y;   // blockDim (32, 8)
#pragma unroll
    for (int i = 0; i < 32; i += 8)
        tile[ty + i][tx] = f2b(inp[(long)(r0 + ty + i) * C + c0 + tx]);
    __syncthreads();
#pragma unroll
    for (int i = 0; i < 32; i += 8)
        outp[(long)(c0 + ty + i) * R + r0 + tx] = tile[tx][ty + i];
}

// =====================================================================
// 256x256 8-phase GEMM (m201 template, plain HIP):
//   BM=BN=256, BK=64, 512 threads = 8 waves (2 x 4).
//   Per C-quadrant (128x128), each wave owns a 64x32 piece; phases walk
//   quadrants (0,0)->(0,1)->(1,1)->(1,0), 16 MFMA per phase per wave.
//   LDS 128 KiB: [buf2][A/B][half2][128*64] bf16, tile-level double buffer.
//
//   SYNC DISCIPLINE (the R1 race fix): vmcnt is PER-WAVE, but half-tiles
//   are staged cooperatively. Therefore every proving VMWAIT(n) sits
//   BEFORE a barrier, and the dependent ds_reads happen AFTER that
//   barrier — only then have ALL waves proven their share landed.
//   Waits: end of ph1 (proves Bhi_t), end of ph2 (proves Ahi_t),
//   end of ph4 (proves Alo/Blo_{t+1}). Never vmcnt(0) in the main loop.
//
//   Swizzle: LDS[row][c] holds global chunk c ^ (row&7) (linear LDS dest +
//   inverse-swizzled global source; ds_read applies the same XOR) ->
//   conflict-free ds_read_b128 at row stride 128 B.
// =====================================================================
#define VMWAIT(n) asm volatile("s_waitcnt vmcnt(" #n ")" ::: "memory")
#define BAR() __builtin_amdgcn_s_barrier()

// stage one half-tile (128 rows x 64 cols bf16) of tile at k0 into lds[p][mat][half]
#define STAGE(mat, half, base, k0, p)                                              \
    do {                                                                           \
        const int _r = tid >> 3;                                                   \
        const int _c = (tid & 7) ^ (_r & 7);                                       \
        const unsigned short* _g =                                                 \
            (base) + (long)((half) * 128 + _r) * K + (k0) + _c * 8;                \
        unsigned short* _lb = &lds[p][mat][half][wave * 512];                      \
        async16(_g, _lb);                                                          \
        async16(_g + 64 * (long)K, _lb + 4096);                                    \
    } while (0)

// load the wave's A fragments for quadrant-row qm (8 x ds_read_b128)
#define LDA(p, qm)                                                                 \
    _Pragma("unroll")                                                              \
    for (int _m = 0; _m < 4; _m++) {                                               \
        _Pragma("unroll")                                                          \
        for (int _kk = 0; _kk < 2; _kk++) {                                        \
            const int _r = wr * 64 + _m * 16 + frow;                               \
            af[_m][_kk] = *(const bf16x8*)                                         \
                &lds[p][0][qm][_r * 64 + (((_kk * 4 + kq) ^ (_r & 7)) * 8)];       \
        }                                                                          \
    }

// load the wave's B fragments for quadrant-col qn (4 x ds_read_b128)
#define LDB(p, qn)                                                                 \
    _Pragma("unroll")                                                              \
    for (int _n = 0; _n < 2; _n++) {                                               \
        _Pragma("unroll")                                                          \
        for (int _kk = 0; _kk < 2; _kk++) {                                        \
            const int _r = wc * 32 + _n * 16 + frow;                               \
            bfr[_n][_kk] = *(const bf16x8*)                                        \
                &lds[p][1][qn][_r * 64 + (((_kk * 4 + kq) ^ (_r & 7)) * 8)];       \
        }                                                                          \
    }

// one C-quadrant x K=64: 16 MFMA, setprio-wrapped (T5)
#define MFMA16(qm, qn)                                                             \
    __builtin_amdgcn_s_setprio(1);                                                 \
    _Pragma("unroll")                                                              \
    for (int _m = 0; _m < 4; _m++) {                                               \
        _Pragma("unroll")                                                          \
        for (int _n = 0; _n < 2; _n++) {                                           \
            _Pragma("unroll")                                                      \
            for (int _kk = 0; _kk < 2; _kk++) {                                    \
                acc[qm][qn][_m][_n] = __builtin_amdgcn_mfma_f32_16x16x32_bf16(     \
                    af[_m][_kk], bfr[_n][_kk], acc[qm][qn][_m][_n], 0, 0, 0);      \
            }                                                                      \
        }                                                                          \
    }                                                                              \
    __builtin_amdgcn_s_setprio(0);

template <bool OUT_BF16>
__global__ __launch_bounds__(512, 2) void gemm256(
    const unsigned short* __restrict__ A,
    const unsigned short* __restrict__ Bt,
    const float* __restrict__ bias,
    void* __restrict__ Cout,
    int N, int K,
    long sA, long sB, long sBias, long sC)
{
    // [buf][A=0/B=1][half][128 rows * 64 cols] bf16 = 128 KiB
    __shared__ __align__(16) unsigned short lds[2][2][2][128 * 64];

    const int tid  = threadIdx.x;
    const int wave = tid >> 6;
    const int lane = tid & 63;
    const int wr   = wave >> 2;     // 0/1 : 64-row slice inside a 128-row quadrant
    const int wc   = wave & 3;      // 0..3: 32-col slice inside a 128-col quadrant
    const int frow = lane & 15;
    const int kq   = lane >> 4;     // k-chunk within 32 (8 bf16 per chunk)
    const long mb  = blockIdx.z;

    const unsigned short* Ag = A  + mb * sA + (long)blockIdx.x * 256 * K;
    const unsigned short* Bg = Bt + mb * sB + (long)blockIdx.y * 256 * K;

    f32x4  acc[2][2][4][2] = {};
    bf16x8 af[4][2];
    bf16x8 bfr[2][2];

    // prologue: stage tile 0 into buf 0, then prove Alo+Blo for ph1's reads.
    STAGE(0, 0, Ag, 0, 0);   // A-lo
    STAGE(1, 0, Bg, 0, 0);   // B-lo
    STAGE(1, 1, Bg, 0, 0);   // B-hi
    STAGE(0, 1, Ag, 0, 0);   // A-hi
    VMWAIT(4);               // Alo, Blo landed (per-wave) ...
    BAR();                   // ... and now for ALL waves

    const int NT = K >> 6;
    for (int t = 0; t < NT - 1; ++t) {
        const int p  = t & 1;
        const int pn = p ^ 1;
        const int k1 = (t + 1) << 6;
        // ph1: quadrant (0,0) — Alo/Blo proven before entry
        LDA(p, 0); LDB(p, 0);
        STAGE(0, 0, Ag, k1, pn);
        BAR();
        MFMA16(0, 0);
        VMWAIT(4);                       // proves Bhi(t) for ph2
        BAR();
        // ph2: quadrant (0,1) — reuse A frags
        LDB(p, 1);
        STAGE(1, 0, Bg, k1, pn);
        BAR();
        MFMA16(0, 1);
        VMWAIT(4);                       // proves Ahi(t) for ph3
        BAR();
        // ph3: quadrant (1,1) — reuse B frags
        LDA(p, 1);
        STAGE(1, 1, Bg, k1, pn);
        BAR();
        MFMA16(1, 1);
        BAR();                           // ph4 re-reads Blo(t): already proven
        // ph4: quadrant (1,0)
        LDB(p, 0);
        STAGE(0, 1, Ag, k1, pn);
        BAR();
        MFMA16(1, 0);
        VMWAIT(4);                       // proves Alo(t+1), Blo(t+1) for next ph1
        BAR();
    }
    // final tile: no staging, drain 4 -> 2 -> 0 (each wait before a barrier,
    // dependent reads after it)
    {
        const int p = (NT - 1) & 1;
        LDA(p, 0); LDB(p, 0);
        MFMA16(0, 0);
        VMWAIT(2); BAR();                // proves Bhi(last)
        LDB(p, 1);
        MFMA16(0, 1);
        VMWAIT(0); BAR();                // proves Ahi(last)
        LDA(p, 1);
        MFMA16(1, 1);
        LDB(p, 0);                       // Blo re-read: proven
        MFMA16(1, 0);
    }

    // epilogue: C/D layout col = lane&15, row = (lane>>4)*4 + e
    const float* bp = bias + mb * sBias;
    const int r_base = blockIdx.x * 256 + wr * 64 + (lane >> 4) * 4;
    const int c_base = blockIdx.y * 256 + wc * 32 + (lane & 15);
#pragma unroll
    for (int qm = 0; qm < 2; qm++) {
#pragma unroll
        for (int qn = 0; qn < 2; qn++) {
#pragma unroll
            for (int m = 0; m < 4; m++) {
#pragma unroll
                for (int n = 0; n < 2; n++) {
                    const int r = r_base + qm * 128 + m * 16;
                    const int c = c_base + qn * 128 + n * 16;
                    const float bv = bp[c];
#pragma unroll
                    for (int e = 0; e < 4; e++) {
                        float v = acc[qm][qn][m][n][e] + bv;
                        if (OUT_BF16)
                            ((unsigned short*)Cout)[mb * sC + (long)(r + e) * N + c] = f2b(v);
                        else
                            ((float*)Cout)[mb * sC + (long)(r + e) * N + c] = v;
                    }
                }
            }
        }
    }
}

// ---------------- LayerNorm + SiLU, in place on bf16 h [M*BI][H] ----------------
__global__ __launch_bounds__(256) void ln_silu(unsigned short* __restrict__ h,
                                               const float* __restrict__ lnw,
                                               const float* __restrict__ lnb) {
    const long row = blockIdx.x;
    const int m = (int)(row >> 12);   // row / BI
    unsigned short* hp = h + row * H_DIM;
    const int tid = threadIdx.x;

    ushort4 raw = *(const ushort4*)(hp + tid * 4);
    float v0 = b2f(raw.x), v1 = b2f(raw.y), v2 = b2f(raw.z), v3 = b2f(raw.w);
    float s  = v0 + v1 + v2 + v3;
    float s2 = v0 * v0 + v1 * v1 + v2 * v2 + v3 * v3;
#pragma unroll
    for (int off = 32; off > 0; off >>= 1) {
        s  += __shfl_down(s,  off, 64);
        s2 += __shfl_down(s2, off, 64);
    }
    __shared__ float wsum[4], wsq[4];
    const int wave = tid >> 6, lane = tid & 63;
    if (lane == 0) { wsum[wave] = s; wsq[wave] = s2; }
    __syncthreads();
    const float S  = wsum[0] + wsum[1] + wsum[2] + wsum[3];
    const float S2 = wsq[0] + wsq[1] + wsq[2] + wsq[3];
    const float mu  = S * (1.0f / H_DIM);
    const float var = S2 * (1.0f / H_DIM) - mu * mu;
    const float rs  = rsqrtf(var + 1e-5f);

    const float* wp = lnw + (long)m * H_DIM + tid * 4;
    const float* bp = lnb + (long)m * H_DIM + tid * 4;
    float t0 = (v0 - mu) * rs * wp[0] + bp[0];
    float t1 = (v1 - mu) * rs * wp[1] + bp[1];
    float t2 = (v2 - mu) * rs * wp[2] + bp[2];
    float t3 = (v3 - mu) * rs * wp[3] + bp[3];
    ushort4 o;
    o.x = f2b(t0 / (1.0f + __expf(-t0)));
    o.y = f2b(t1 / (1.0f + __expf(-t1)));
    o.z = f2b(t2 / (1.0f + __expf(-t2)));
    o.w = f2b(t3 / (1.0f + __expf(-t3)));
    *(ushort4*)(hp + tid * 4) = o;
}

extern "C" void kernel_launch(void* const* d_in, const int* in_sizes, int n_in,
                              void* d_out, int out_size, void* d_ws, size_t ws_size,
                              hipStream_t stream) {
    (void)in_sizes; (void)n_in; (void)out_size; (void)ws_size;
    const float* x   = (const float*)d_in[0];
    const float* W1  = (const float*)d_in[1];
    const float* b1  = (const float*)d_in[2];
    const float* lnw = (const float*)d_in[3];
    const float* lnb = (const float*)d_in[4];
    const float* W2  = (const float*)d_in[5];
    const float* b2  = (const float*)d_in[6];
    float* out = (float*)d_out;

    const size_t nX  = (size_t)M_MEMBERS * BI_DIM * E_DIM;   // 16,777,216
    const size_t nW1 = (size_t)M_MEMBERS * E_DIM * H_DIM;    //  4,194,304
    const size_t nW2 = (size_t)M_MEMBERS * H_DIM * V_DIM;    // 33,554,432
    // ws layout (bf16 elems): xb | w1t | w2t | hb   -> 176 MB total
    unsigned short* xb  = (unsigned short*)d_ws;
    unsigned short* w1t = xb  + nX;
    unsigned short* w2t = w1t + nW1;
    unsigned short* hb  = w2t + nW2;

    cvt_bf16<<<(unsigned)(nX / 1024), 256, 0, stream>>>(x, xb, (long)nX);
    cvt_t<<<dim3(H_DIM / 32, E_DIM / 32, M_MEMBERS), dim3(32, 8), 0, stream>>>(W1, w1t, E_DIM, H_DIM);
    cvt_t<<<dim3(V_DIM / 32, H_DIM / 32, M_MEMBERS), dim3(32, 8), 0, stream>>>(W2, w2t, H_DIM, V_DIM);

    // GEMM1: h = x @ W1 + b1  (bf16 out, pre-LN)
    gemm256<true><<<dim3(BI_DIM / 256, H_DIM / 256, M_MEMBERS), 512, 0, stream>>>(
        xb, w1t, b1, hb, H_DIM, E_DIM,
        (long)BI_DIM * E_DIM, (long)H_DIM * E_DIM, (long)H_DIM, (long)BI_DIM * H_DIM);

    ln_silu<<<dim3(M_MEMBERS * BI_DIM), 256, 0, stream>>>(hb, lnw, lnb);

    // GEMM2: out = h @ W2 + b2  (fp32 out)
    gemm256<false><<<dim3(BI_DIM / 256, V_DIM / 256, M_MEMBERS), 512, 0, stream>>>(
        hb, w2t, b2, out, V_DIM, H_DIM,
        (long)BI_DIM * H_DIM, (long)V_DIM * H_DIM, (long)V_DIM, (long)BI_DIM * V_DIM);
}